// Round 10
// baseline (63.643 us; speedup 1.0000x reference)
//
#include <hip/hip_runtime.h>
#include <math.h>

#define FAR_DELTA 1e10f

// Software-pipelined grid-stride: each wave processes 4 quads (16 rays) as
// 2 unrolled trips of a ping-pong double buffer. The NEXT tile's 10 float4
// loads are issued before computing the CURRENT tile, so every wave keeps
// ~10KB of loads outstanding continuously (including during its compute
// tail). No min-waves launch bound: the allocator must hold 2 tiles live
// (~80 VGPR data) — 4 waves/SIMD occupancy is the deliberate trade.
struct Tile {
    float4 zvA, dvA, zvB, dvB;
    float4 fA0, fA1, fA2, fB0, fB1, fB2;
};

__device__ __forceinline__ void load_tile(Tile& t, int q, int li, int half,
                                          const float* __restrict__ density,
                                          const float* __restrict__ feature,
                                          const float* __restrict__ depth) {
    const int rayA = q * 4 + half;
    const int rayB = q * 4 + 2 + half;
    const size_t baseA = (size_t)rayA * 128 + (size_t)li * 4;
    const size_t baseB = (size_t)rayB * 128 + (size_t)li * 4;
    t.zvA = *reinterpret_cast<const float4*>(depth   + baseA);
    t.dvA = *reinterpret_cast<const float4*>(density + baseA);
    t.zvB = *reinterpret_cast<const float4*>(depth   + baseB);
    t.dvB = *reinterpret_cast<const float4*>(density + baseB);
    const float4* fpA = reinterpret_cast<const float4*>(feature + baseA * 3);
    const float4* fpB = reinterpret_cast<const float4*>(feature + baseB * 3);
    t.fA0 = fpA[0]; t.fA1 = fpA[1]; t.fA2 = fpA[2];
    t.fB0 = fpB[0]; t.fB1 = fpB[1]; t.fB2 = fpB[2];
}

__device__ __forceinline__ void compute_store(const Tile& t, int q, int li, int half,
                                              float* __restrict__ feat_out,
                                              float* __restrict__ depth_out) {
    const int rayA = q * 4 + half;
    const int rayB = q * 4 + 2 + half;

    float znA = __shfl_down(t.zvA.x, 1);
    float znB = __shfl_down(t.zvB.x, 1);

    float a0 = t.dvA.x * (t.zvA.y - t.zvA.x);
    float a1 = t.dvA.y * (t.zvA.z - t.zvA.y);
    float a2 = t.dvA.z * (t.zvA.w - t.zvA.z);
    float a3 = t.dvA.w * ((li == 31) ? FAR_DELTA : (znA - t.zvA.w));
    float b0 = t.dvB.x * (t.zvB.y - t.zvB.x);
    float b1 = t.dvB.y * (t.zvB.z - t.zvB.y);
    float b2 = t.dvB.z * (t.zvB.w - t.zvB.z);
    float b3 = t.dvB.w * ((li == 31) ? FAR_DELTA : (znB - t.zvB.w));

    float lsumA = a0 + a1 + a2 + ((li == 31) ? 0.0f : a3);
    float lsumB = b0 + b1 + b2 + ((li == 31) ? 0.0f : b3);

    float sA = lsumA, sB = lsumB;
    #pragma unroll
    for (int off = 1; off < 32; off <<= 1) {
        float nA = __shfl_up(sA, off);
        float nB = __shfl_up(sB, off);
        if (li >= off) { sA += nA; sB += nB; }
    }
    float cA0 = sA - lsumA;
    float cB0 = sB - lsumB;
    float cA1 = cA0 + a0, cA2 = cA1 + a1, cA3 = cA2 + a2;
    float cB1 = cB0 + b0, cB2 = cB1 + b1, cB3 = cB2 + b2;

    float EA0 = __expf(-cA0), EA1 = __expf(-cA1), EA2 = __expf(-cA2),
          EA3 = __expf(-cA3), EA4 = __expf(-(cA3 + a3));
    float EB0 = __expf(-cB0), EB1 = __expf(-cB1), EB2 = __expf(-cB2),
          EB3 = __expf(-cB3), EB4 = __expf(-(cB3 + b3));

    float wA0 = EA0 - EA1, wA1 = EA1 - EA2, wA2 = EA2 - EA3, wA3 = EA3 - EA4;
    float wB0 = EB0 - EB1, wB1 = EB1 - EB2, wB2 = EB2 - EB3, wB3 = EB3 - EB4;

    float rA = wA0 * t.fA0.x + wA1 * t.fA0.w + wA2 * t.fA1.z + wA3 * t.fA2.y;
    float gA = wA0 * t.fA0.y + wA1 * t.fA1.x + wA2 * t.fA1.w + wA3 * t.fA2.z;
    float bA = wA0 * t.fA0.z + wA1 * t.fA1.y + wA2 * t.fA2.x + wA3 * t.fA2.w;
    float dA = wA0 * t.zvA.x + wA1 * t.zvA.y + wA2 * t.zvA.z + wA3 * t.zvA.w;
    float rB = wB0 * t.fB0.x + wB1 * t.fB0.w + wB2 * t.fB1.z + wB3 * t.fB2.y;
    float gB = wB0 * t.fB0.y + wB1 * t.fB1.x + wB2 * t.fB1.w + wB3 * t.fB2.z;
    float bB = wB0 * t.fB0.z + wB1 * t.fB1.y + wB2 * t.fB2.x + wB3 * t.fB2.w;
    float dB = wB0 * t.zvB.x + wB1 * t.zvB.y + wB2 * t.zvB.z + wB3 * t.zvB.w;

    #pragma unroll
    for (int off = 16; off >= 1; off >>= 1) {
        rA += __shfl_xor(rA, off);  gA += __shfl_xor(gA, off);
        bA += __shfl_xor(bA, off);  dA += __shfl_xor(dA, off);
        rB += __shfl_xor(rB, off);  gB += __shfl_xor(gB, off);
        bB += __shfl_xor(bB, off);  dB += __shfl_xor(dB, off);
    }

    if (li == 0) {
        feat_out[(size_t)rayA * 3 + 0] = rA;
        feat_out[(size_t)rayA * 3 + 1] = gA;
        feat_out[(size_t)rayA * 3 + 2] = bA;
        depth_out[rayA] = dA;
        feat_out[(size_t)rayB * 3 + 0] = rB;
        feat_out[(size_t)rayB * 3 + 1] = gB;
        feat_out[(size_t)rayB * 3 + 2] = bB;
        depth_out[rayB] = dB;
    }
}

__global__ __launch_bounds__(256) void volrend_kernel(
    const float* __restrict__ density,   // (B,128,1) f32
    const float* __restrict__ feature,   // (B,128,3) f32
    const float* __restrict__ depth,     // (B,128)   f32
    float* __restrict__ feat_out,        // (B,3) f32
    float* __restrict__ depth_out,       // (B,1) f32
    int B)
{
    const int lane = threadIdx.x & 63;
    const int li   = lane & 31;
    const int half = lane >> 5;
    const int widb = threadIdx.x >> 6;
    const int wpb  = blockDim.x >> 6;
    const int wave = blockIdx.x * wpb + widb;
    const int nwav = gridDim.x * wpb;          // 8192
    const int nquad = B >> 2;                  // 32768

    Tile T0, T1;
    int q0 = wave;
    if (q0 >= nquad) return;
    load_tile(T0, q0, li, half, density, feature, depth);

    // ping-pong: prefetch next tile before computing current
    while (true) {
        int q1 = q0 + nwav;
        if (q1 < nquad) load_tile(T1, q1, li, half, density, feature, depth);
        compute_store(T0, q0, li, half, feat_out, depth_out);
        if (q1 >= nquad) return;

        int q2 = q1 + nwav;
        if (q2 < nquad) load_tile(T0, q2, li, half, density, feature, depth);
        compute_store(T1, q1, li, half, feat_out, depth_out);
        if (q2 >= nquad) return;
        q0 = q2;
    }
}

extern "C" void kernel_launch(void* const* d_in, const int* in_sizes, int n_in,
                              void* d_out, int out_size, void* d_ws, size_t ws_size,
                              hipStream_t stream) {
    const float* density = (const float*)d_in[0];
    const float* feature = (const float*)d_in[1];
    const float* depth   = (const float*)d_in[2];
    const int N = 128;
    const int B = in_sizes[2] / N;                 // depth_values is (B,N)

    float* feat_out  = (float*)d_out;              // (B,3) flat f32
    float* depth_out = feat_out + (size_t)B * 3;   // (B,1) flat f32

    dim3 block(256);
    dim3 grid(2048);                               // 8192 waves, 4 quads each
    hipLaunchKernelGGL(volrend_kernel, grid, block, 0, stream,
                       density, feature, depth, feat_out, depth_out, B);
}

// Round 11
// 59.216 us; speedup vs baseline: 1.0748x; 1.0748x over previous
//
#include <hip/hip_runtime.h>
#include <math.h>

#define FAR_DELTA 1e10f

// Round-8 structure (best: 60.0 us) + shortened serial chain.
// Half-wave per ray: lanes 0-31 own ray A, lanes 32-63 own ray B; one
// ray-pair per wave, one-shot (no loop) -> 65536 short waves, latency
// hidden by wave turnover; short wave lifetime minimizes the drain tail.
// Lane li owns samples 4*li..4*li+3. Loads: depth+density first, features
// last (scan runs while features are still in flight). Transmittance in
// exclusive form: w_j = E_j - E_{j+1}, E_j = __expf(-cum_j) -> 5
// independent exps after a 3-add chain (no serial product). FAR sample:
// E_4 = exp(-~1e9) = 0 exactly; huge tau never enters the scan.
__global__ __launch_bounds__(256, 8) void volrend_kernel(
    const float* __restrict__ density,   // (B,128,1) f32
    const float* __restrict__ feature,   // (B,128,3) f32
    const float* __restrict__ depth,     // (B,128)   f32
    float* __restrict__ feat_out,        // (B,3) f32
    float* __restrict__ depth_out,       // (B,1) f32
    int B)
{
    const int lane = threadIdx.x & 63;
    const int li   = lane & 31;          // lane within half-wave
    const int half = lane >> 5;          // 0 = ray A, 1 = ray B
    const int widb = threadIdx.x >> 6;
    const int wpb  = blockDim.x >> 6;
    const int p    = blockIdx.x * wpb + widb;   // one pair per wave
    const int npairs = B >> 1;
    if (p >= npairs) return;

    const int ray = p * 2 + half;
    const size_t base = (size_t)ray * 128 + (size_t)li * 4;

    float4 zv = *reinterpret_cast<const float4*>(depth   + base);
    float4 dv = *reinterpret_cast<const float4*>(density + base);
    const float4* fp = reinterpret_cast<const float4*>(feature + base * 3);
    float4 f0 = fp[0];               // r0 g0 b0 r1
    float4 f1 = fp[1];               // g1 b1 r2 g2
    float4 f2 = fp[2];               // b2 r3 g3 b3

    // deltas: 3 in-lane, 1 from next lane (FAR for last sample of ray)
    float zn = __shfl_down(zv.x, 1);
    float t0 = dv.x * (zv.y - zv.x);
    float t1 = dv.y * (zv.z - zv.y);
    float t2 = dv.z * (zv.w - zv.z);
    float t3 = dv.w * ((li == 31) ? FAR_DELTA : (zn - zv.w));

    // per-lane tau sum for the scan; exclude the huge FAR tau
    float lsum = t0 + t1 + t2 + ((li == 31) ? 0.0f : t3);

    // inclusive scan within each 32-lane half (guard blocks cross-half pulls)
    float s = lsum;
    #pragma unroll
    for (int off = 1; off < 32; off <<= 1) {
        float n = __shfl_up(s, off);
        if (li >= off) s += n;
    }
    float c0 = s - lsum;             // exclusive prefix before sample 4*li
    float c1 = c0 + t0, c2 = c1 + t1, c3 = c2 + t2;

    // 5 independent exps; E4 = 0 for the FAR sample (c3 + t3 ~ 1e9)
    float E0 = __expf(-c0), E1 = __expf(-c1), E2 = __expf(-c2),
          E3 = __expf(-c3), E4 = __expf(-(c3 + t3));

    float w0 = E0 - E1, w1 = E1 - E2, w2 = E2 - E3, w3 = E3 - E4;

    float r  = w0 * f0.x + w1 * f0.w + w2 * f1.z + w3 * f2.y;
    float g  = w0 * f0.y + w1 * f1.x + w2 * f1.w + w3 * f2.z;
    float b  = w0 * f0.z + w1 * f1.y + w2 * f2.x + w3 * f2.w;
    float dz = w0 * zv.x + w1 * zv.y + w2 * zv.z + w3 * zv.w;

    // butterfly over each half (xor of bits 0..4 never crosses halves)
    #pragma unroll
    for (int off = 16; off >= 1; off >>= 1) {
        r  += __shfl_xor(r,  off);
        g  += __shfl_xor(g,  off);
        b  += __shfl_xor(b,  off);
        dz += __shfl_xor(dz, off);
    }

    if (li == 0) {                   // lanes 0 and 32 write their rays
        feat_out[(size_t)ray * 3 + 0] = r;
        feat_out[(size_t)ray * 3 + 1] = g;
        feat_out[(size_t)ray * 3 + 2] = b;
        depth_out[ray] = dz;
    }
}

extern "C" void kernel_launch(void* const* d_in, const int* in_sizes, int n_in,
                              void* d_out, int out_size, void* d_ws, size_t ws_size,
                              hipStream_t stream) {
    const float* density = (const float*)d_in[0];
    const float* feature = (const float*)d_in[1];
    const float* depth   = (const float*)d_in[2];
    const int N = 128;
    const int B = in_sizes[2] / N;                 // depth_values is (B,N)

    float* feat_out  = (float*)d_out;              // (B,3) flat f32
    float* depth_out = feat_out + (size_t)B * 3;   // (B,1) flat f32

    const int npairs = B >> 1;                     // 65536
    const int wavesPerBlock = 4;                   // 256 threads
    dim3 block(256);
    dim3 grid((npairs + wavesPerBlock - 1) / wavesPerBlock);  // 16384 blocks
    hipLaunchKernelGGL(volrend_kernel, grid, block, 0, stream,
                       density, feature, depth, feat_out, depth_out, B);
}